// Round 16
// baseline (218.462 us; speedup 1.0000x reference)
//
#include <hip/hip_runtime.h>
#include <cstdint>
#include <cstddef>

// Round 16: critical-path shortening. (1) k_h4 phase-1 (wlu=M@x+WlUP,
// afp=Wl@x) depends only on xT -> hoisted into launch 1 (k_qkh, 1024 blocks
// = 512 qk + 512 h4p1, concurrent). k_h5 = P-GEMM + epilogue only (9KB LDS).
// wlu bf16 rounding point identical to R15's LDS pass; afp fp32. (2) k_att
// split to 512 blocks (16-row g-tiles): per-thread trig halved (32x8),
// 2 blocks/CU. Layer critical path ~36 -> ~23 us.

#define BB 64      // batch
#define CH 256     // channels
#define NP 128     // points
#define DQ 64      // q/k dim
#define NLAYERS 4

#define ANG_REV    0.6079271018540267f   // (180/(pi*15)) / (2*pi)
#define DIV_STEP   0.28782313662425575f  // ln(10000)/32

#define LROW 264   // padded LDS row stride (u16) for 256-wide tiles
#define LROW2 136  // padded LDS row stride (u16) for 128-wide WlU tiles

typedef unsigned short u16;
typedef __attribute__((ext_vector_type(8))) short sh8;   // 8 bf16 = 4 VGPR
typedef __attribute__((ext_vector_type(4))) float f32x4; // MFMA C/D
#define MFMA(a, b, c) __builtin_amdgcn_mfma_f32_16x16x32_bf16(a, b, c, 0, 0, 0)

static __device__ __forceinline__ u16 f2bf(float x) {
  unsigned u = __float_as_uint(x);
  return (u16)((u + 0x7FFFu + ((u >> 16) & 1u)) >> 16);
}
static __device__ __forceinline__ float bf2f(u16 h) {
  return __uint_as_float(((unsigned)h) << 16);
}
// HW trig, input in REVOLUTIONS (valid: our args bounded by +-0.61 rev)
static __device__ __forceinline__ float hw_sin(float rev) {
  float r;
  asm("v_sin_f32 %0, %1" : "=v"(r) : "v"(rev));
  return r;
}
static __device__ __forceinline__ float hw_cos(float rev) {
  float r;
  asm("v_cos_f32 %0, %1" : "=v"(r) : "v"(rev));
  return r;
}

// ---------------------------------------------------------------------------
// Merged init (2568 blocks): weight cvts, transposes, emb2 bf16.
__global__ __launch_bounds__(256) void k_init(
    const float* __restrict__ Wv, const float* __restrict__ Wvp,
    const float* __restrict__ Wl, const float* __restrict__ Wq,
    const float* __restrict__ Wk, const float* __restrict__ p1w,
    const float* __restrict__ p2w, const float* __restrict__ pca,
    const float* __restrict__ lrf, const float* __restrict__ ac,
    u16* __restrict__ Wlbf, u16* __restrict__ Wqhi, u16* __restrict__ Wqlo,
    u16* __restrict__ Wkhi, u16* __restrict__ Wklo, u16* __restrict__ p1wT,
    u16* __restrict__ p2wbf, u16* __restrict__ pThi, u16* __restrict__ pTlo,
    u16* __restrict__ xThi, u16* __restrict__ xTlo,
    u16* __restrict__ WvT, u16* __restrict__ WvpT, u16* __restrict__ emb2bf)
{
  __shared__ __align__(16) float tl[64 * 65];
  int blk = blockIdx.x, tid = threadIdx.x;
  if (blk < 256) {
    int i = (blk * 256 + tid) * 4;
    float4 v = *(const float4*)(Wl + i);
    u16 o[4] = {f2bf(v.x), f2bf(v.y), f2bf(v.z), f2bf(v.w)};
    *(uint2*)(Wlbf + i) = *(const uint2*)o;
  } else if (blk < 384) {
    int bb = blk - 256;
    const float* s = (bb < 64) ? Wq : Wk;
    u16* dh = (bb < 64) ? Wqhi : Wkhi;
    u16* dl = (bb < 64) ? Wqlo : Wklo;
    int i = ((bb & 63) * 256 + tid) * 4;
    float4 v = *(const float4*)(s + i);
    float vv[4] = {v.x, v.y, v.z, v.w};
    u16 h[4], l[4];
#pragma unroll
    for (int r = 0; r < 4; r++) {
      h[r] = f2bf(vv[r]);
      l[r] = f2bf(vv[r] - bf2f(h[r]));
    }
    *(uint2*)(dh + i) = *(const uint2*)h;
    *(uint2*)(dl + i) = *(const uint2*)l;
  } else if (blk < 388) {
    int l = blk - 384;
    const float* src = p1w + (size_t)l * DQ * DQ;
    u16* dst = p1wT + (size_t)l * DQ * DQ;
#pragma unroll
    for (int i = 0; i < 16; i++) {
      int idx = tid + i * 256;
      int dd = idx >> 6, oo = idx & 63;
      dst[idx] = f2bf(src[oo * DQ + dd]);
    }
  } else if (blk < 392) {
    int l = blk - 388;
    const float* src = p2w + (size_t)l * DQ * DQ;
    u16* dst = p2wbf + (size_t)l * DQ * DQ;
#pragma unroll
    for (int i = 0; i < 16; i++) {
      int idx = tid + i * 256;
      dst[idx] = f2bf(src[idx]);
    }
  } else if (blk < 1416) {
    int bi = blk - 392;
    int nt = bi & 1, y = (bi >> 1) & 7, b = bi >> 4;
    int ct = y & 3, is_lrf = y >> 2;
    const float* x = is_lrf ? lrf : pca;
    u16* hiT = is_lrf ? xThi : pThi;
    u16* loT = is_lrf ? xTlo : pTlo;
    {
      int col = tid & 63, rq = tid >> 6;
      const float* src = x + (size_t)b * CH * NP + (size_t)(ct * 64) * NP + nt * 64;
#pragma unroll
      for (int i = 0; i < 16; i++) {
        int c = rq + i * 4;
        tl[col * 65 + c] = src[(size_t)c * NP + col];
      }
    }
    __syncthreads();
    {
      int cloc = tid & 63, nq = tid >> 6;
#pragma unroll
      for (int i = 0; i < 16; i++) {
        int n = nq + i * 4;
        float v = tl[n * 65 + cloc];
        u16 h = f2bf(v);
        u16 l = f2bf(v - bf2f(h));
        size_t off = ((size_t)b * NP + nt * 64 + n) * CH + ct * 64 + cloc;
        hiT[off] = h;
        loT[off] = l;
      }
    }
  } else if (blk < 1544) {
    int bi = blk - 1416;
    int mat = bi >> 4, t = bi & 15;
    int l = mat & 3;
    const float* src = ((mat < 4) ? Wv : Wvp) + (size_t)l * CH * CH;
    u16* dst = ((mat < 4) ? WvT : WvpT) + (size_t)l * CH * CH;
    int tr = t >> 2, tc = t & 3;
    {
      int col = tid & 63, rq = tid >> 6;
#pragma unroll
      for (int i = 0; i < 16; i++) {
        int co = rq + i * 4;
        tl[col * 65 + co] = src[(size_t)(tr * 64 + co) * CH + tc * 64 + col];
      }
    }
    __syncthreads();
    {
      int cloc = tid & 63, nq = tid >> 6;
#pragma unroll
      for (int i = 0; i < 16; i++) {
        int n = nq + i * 4;
        dst[(size_t)(tc * 64 + n) * CH + tr * 64 + cloc] = f2bf(tl[n * 65 + cloc]);
      }
    }
  } else {
    int bi = blk - 1544;
    int row0 = bi * 8;
    int r = tid >> 5, j = tid & 31;
    int row = row0 + r;
    float a = ac[row];
    float rev = a * ANG_REV * __expf(-(float)j * DIV_STEP);
    emb2bf[(size_t)row * DQ + 2 * j] = f2bf(hw_sin(rev));
    emb2bf[(size_t)row * DQ + 2 * j + 1] = f2bf(hw_cos(rev));
  }
}

// ---------------------------------------------------------------------------
// M[l] = bx*Wl@Wv, M2[l] = (1-bx)*Wl@Wvp, bf16 [c'][c] (k=c contiguous).
__global__ __launch_bounds__(256) void k_mm(
    const u16* __restrict__ WvT, const u16* __restrict__ WvpT,
    const u16* __restrict__ Wlbf, const float* __restrict__ beta_x,
    u16* __restrict__ Mb, u16* __restrict__ M2b)
{
  int tid = threadIdx.x, lane = tid & 63;
  int lm = lane & 15, lk = lane >> 4;
  int tt = blockIdx.x * 4 + (tid >> 6);
  int which = tt >> 8, rest = tt & 255;
  int l = rest >> 6, t = rest & 63;
  int tcp = t >> 3, tcc = t & 7;
  const u16* WT = (which ? WvpT : WvT) + (size_t)l * CH * CH;
  const u16* A0 = WT + ((size_t)(tcc * 32) + lm) * CH + lk * 8;
  const u16* A1 = A0 + 16 * CH;
  const u16* B0 = Wlbf + (size_t)l * CH * CH + ((size_t)(tcp * 32) + lm) * CH + lk * 8;
  const u16* B1 = B0 + 16 * CH;
  f32x4 a00 = {}, a01 = {}, a10 = {}, a11 = {};
#pragma unroll
  for (int ks = 0; ks < 8; ks++) {
    int o = ks * 32;
    sh8 a0 = *(const sh8*)(A0 + o), a1 = *(const sh8*)(A1 + o);
    sh8 b0 = *(const sh8*)(B0 + o), b1 = *(const sh8*)(B1 + o);
    a00 = MFMA(a0, b0, a00);
    a01 = MFMA(a0, b1, a01);
    a10 = MFMA(a1, b0, a10);
    a11 = MFMA(a1, b1, a11);
  }
  float bx = beta_x[l];
  float sc = which ? (1.0f - bx) : bx;
  u16* out = (which ? M2b : Mb) + (size_t)l * CH * CH;
  f32x4 acc[2][2] = {{a00, a01}, {a10, a11}};
#pragma unroll
  for (int i = 0; i < 2; i++)
#pragma unroll
    for (int j = 0; j < 2; j++) {
      int c0 = tcc * 32 + i * 16 + lk * 4;
      int cp = tcp * 32 + j * 16 + lm;
      u16 ov[4];
#pragma unroll
      for (int r = 0; r < 4; r++) ov[r] = f2bf(sc * acc[i][j][r]);
      *(uint2*)&out[(size_t)cp * CH + c0] = *(const uint2*)ov;
    }
}

// ---------------------------------------------------------------------------
#define STAGE_W(dst, src)                                                    \
  _Pragma("unroll")                                                          \
  for (int it = 0; it < 4; it++) {                                           \
    int idx = threadIdx.x + it * 256, row = idx >> 5, ch = idx & 31;         \
    *(uint4*)&dst[row * LROW + ch * 8] =                                     \
        *(const uint4*)(src + row * 256 + ch * 8);                           \
  }

// ---------------------------------------------------------------------------
// [0,512): KP2A[l] = split(Wq[l]@pca + emb2@p2w[l]^T + p2b[l]);
// [512,2560): WlUPA[l][b][n][c'] = bf(M2[l]@pca).
__global__ __launch_bounds__(256) void k_pre2(
    const u16* __restrict__ pThi, const u16* __restrict__ pTlo,
    const u16* __restrict__ Wqhi, const u16* __restrict__ Wqlo,
    const u16* __restrict__ M2b, const u16* __restrict__ p2wbf,
    const u16* __restrict__ emb2bf, const float* __restrict__ p2b,
    u16* __restrict__ KP2hiA, u16* __restrict__ KP2loA, u16* __restrict__ WlUPA)
{
  __shared__ __align__(16) u16 WS[2 * 32 * LROW];
  int tid = threadIdx.x, lane = tid & 63;
  int lm = lane & 15, lk = lane >> 4;
  if (blockIdx.x < 512) {
    int bi = blockIdx.x;
    int l = bi >> 7, rest = bi & 127;
    int dt = rest >> 6, b = rest & 63;
    int nt = tid >> 6;
    u16* WH = WS;
    u16* WL = WS + 32 * LROW;
    {
      const u16* sH = Wqhi + (size_t)l * DQ * CH + (size_t)dt * 32 * CH;
      const u16* sL = Wqlo + (size_t)l * DQ * CH + (size_t)dt * 32 * CH;
      STAGE_W(WH, sH)
      STAGE_W(WL, sL)
    }
    __syncthreads();
    const u16* B0h = pThi + ((size_t)b * NP + nt * 32 + lm) * CH + lk * 8;
    const u16* B1h = B0h + 16 * CH;
    const u16* B0l = pTlo + ((size_t)b * NP + nt * 32 + lm) * CH + lk * 8;
    const u16* B1l = B0l + 16 * CH;
    f32x4 acc[2][2] = {};
#pragma unroll
    for (int kb = 0; kb < 4; kb++) {
      sh8 rb0h[2], rb1h[2], rb0l[2], rb1l[2];
#pragma unroll
      for (int u = 0; u < 2; u++) {
        int o = (kb * 2 + u) * 32;
        rb0h[u] = *(const sh8*)(B0h + o); rb1h[u] = *(const sh8*)(B1h + o);
        rb0l[u] = *(const sh8*)(B0l + o); rb1l[u] = *(const sh8*)(B1l + o);
      }
#pragma unroll
      for (int u = 0; u < 2; u++) {
        int o2 = (kb * 2 + u) * 32 + lk * 8;
        sh8 a0h = *(const sh8*)&WH[lm * LROW + o2];
        sh8 a1h = *(const sh8*)&WH[(16 + lm) * LROW + o2];
        sh8 a0l = *(const sh8*)&WL[lm * LROW + o2];
        sh8 a1l = *(const sh8*)&WL[(16 + lm) * LROW + o2];
        acc[0][0] = MFMA(a0h, rb0h[u], acc[0][0]);
        acc[0][0] = MFMA(a0h, rb0l[u], acc[0][0]);
        acc[0][0] = MFMA(a0l, rb0h[u], acc[0][0]);
        acc[0][1] = MFMA(a0h, rb1h[u], acc[0][1]);
        acc[0][1] = MFMA(a0h, rb1l[u], acc[0][1]);
        acc[0][1] = MFMA(a0l, rb1h[u], acc[0][1]);
        acc[1][0] = MFMA(a1h, rb0h[u], acc[1][0]);
        acc[1][0] = MFMA(a1h, rb0l[u], acc[1][0]);
        acc[1][0] = MFMA(a1l, rb0h[u], acc[1][0]);
        acc[1][1] = MFMA(a1h, rb1h[u], acc[1][1]);
        acc[1][1] = MFMA(a1h, rb1l[u], acc[1][1]);
        acc[1][1] = MFMA(a1l, rb1h[u], acc[1][1]);
      }
    }
    {
      const u16* A20 = p2wbf + (size_t)l * DQ * DQ + ((size_t)(dt * 32) + lm) * DQ + lk * 8;
      const u16* A21 = A20 + 16 * DQ;
      const u16* B20 = emb2bf + ((size_t)b * NP + nt * 32 + lm) * DQ + lk * 8;
      const u16* B21 = B20 + 16 * DQ;
#pragma unroll
      for (int ks = 0; ks < 2; ks++) {
        int o = ks * 32;
        sh8 a0 = *(const sh8*)(A20 + o), a1 = *(const sh8*)(A21 + o);
        sh8 b0 = *(const sh8*)(B20 + o), b1 = *(const sh8*)(B21 + o);
        acc[0][0] = MFMA(a0, b0, acc[0][0]);
        acc[0][1] = MFMA(a0, b1, acc[0][1]);
        acc[1][0] = MFMA(a1, b0, acc[1][0]);
        acc[1][1] = MFMA(a1, b1, acc[1][1]);
      }
    }
#pragma unroll
    for (int i = 0; i < 2; i++)
#pragma unroll
      for (int j = 0; j < 2; j++) {
        int n = nt * 32 + j * 16 + lm;
        int d0 = dt * 32 + i * 16 + lk * 4;
        size_t off = (((size_t)l * BB + b) * NP + n) * DQ + d0;
        f32x4 v = acc[i][j];
        u16 h[4], lo[4];
#pragma unroll
        for (int r2 = 0; r2 < 4; r2++) {
          float vv = v[r2] + p2b[l * DQ + d0 + r2];
          h[r2] = f2bf(vv);
          lo[r2] = f2bf(vv - bf2f(h[r2]));
        }
        *(uint2*)&KP2hiA[off] = *(const uint2*)h;
        *(uint2*)&KP2loA[off] = *(const uint2*)lo;
      }
  } else {
    int bi = blockIdx.x - 512;
    int l = bi >> 9, rest = bi & 511;
    int ct = rest >> 6, b = rest & 63;
    int nt = tid >> 6;
    {
      const u16* sH = M2b + (size_t)l * CH * CH + (size_t)ct * 32 * CH;
      STAGE_W(WS, sH)
    }
    __syncthreads();
    const u16* X0 = pThi + ((size_t)b * NP + nt * 32 + lm) * CH + lk * 8;
    const u16* X1 = X0 + 16 * CH;
    f32x4 a00 = {}, a01 = {}, a10 = {}, a11 = {};
#pragma unroll
    for (int kb = 0; kb < 2; kb++) {
      sh8 rx0[4], rx1[4];
#pragma unroll
      for (int u = 0; u < 4; u++) {
        int o = (kb * 4 + u) * 32;
        rx0[u] = *(const sh8*)(X0 + o); rx1[u] = *(const sh8*)(X1 + o);
      }
#pragma unroll
      for (int u = 0; u < 4; u++) {
        int o2 = (kb * 4 + u) * 32 + lk * 8;
        sh8 w0 = *(const sh8*)&WS[lm * LROW + o2];
        sh8 w1 = *(const sh8*)&WS[(16 + lm) * LROW + o2];
        a00 = MFMA(w0, rx0[u], a00);
        a01 = MFMA(w0, rx1[u], a01);
        a10 = MFMA(w1, rx0[u], a10);
        a11 = MFMA(w1, rx1[u], a11);
      }
    }
    f32x4 acc[2][2] = {{a00, a01}, {a10, a11}};
#pragma unroll
    for (int i = 0; i < 2; i++)
#pragma unroll
      for (int j = 0; j < 2; j++) {
        int c0 = ct * 32 + i * 16 + lk * 4;
        int n = nt * 32 + j * 16 + lm;
        u16 ov[4];
#pragma unroll
        for (int r2 = 0; r2 < 4; r2++) ov[r2] = f2bf(acc[i][j][r2]);
        *(uint2*)&WlUPA[(((size_t)l * BB + b) * NP + n) * CH + c0] = *(const uint2*)ov;
      }
  }
}

// ---------------------------------------------------------------------------
// Launch 1 per layer (1024 blocks). [0,512): QK projections (2mat x 2dt x
// 64b x 2nh; wave = 16-row n-tile). [512,1024): value phase-1 (ct,b):
// WlU[b][c'][n] = bf(M@x + WlUP), Afp[b][c'][n] = Wl@x (fp32).
__global__ __launch_bounds__(256) void k_qkh(
    const u16* __restrict__ xThi, const u16* __restrict__ xTlo,
    const u16* __restrict__ Wqhi, const u16* __restrict__ Wqlo,
    const u16* __restrict__ Wkhi, const u16* __restrict__ Wklo,
    const u16* __restrict__ Mb, const u16* __restrict__ Wlbf,
    const u16* __restrict__ WlUP,
    u16* __restrict__ XQhi, u16* __restrict__ XQlo,
    u16* __restrict__ KLThi, u16* __restrict__ KLTlo,
    u16* __restrict__ WlU, float* __restrict__ Afp)
{
  __shared__ __align__(16) u16 WS[2 * 32 * LROW];
  int tid = threadIdx.x, lane = tid & 63, wave = tid >> 6;
  int lm = lane & 15, lk = lane >> 4;
  if (blockIdx.x < 512) {
    int bi = blockIdx.x;
    int mat = bi >> 8, r = bi & 255;
    int dt = r >> 7, r2 = r & 127;
    int nh = r2 >> 6, b = r2 & 63;
    u16* WH = WS;
    u16* WL = WS + 32 * LROW;
    {
      const u16* sH = (mat ? Wkhi : Wqhi) + (size_t)dt * 32 * CH;
      const u16* sL = (mat ? Wklo : Wqlo) + (size_t)dt * 32 * CH;
      STAGE_W(WH, sH)
      STAGE_W(WL, sL)
    }
    __syncthreads();
    int n0 = nh * 64 + wave * 16;
    const u16* B0h = xThi + ((size_t)b * NP + n0 + lm) * CH + lk * 8;
    const u16* B0l = xTlo + ((size_t)b * NP + n0 + lm) * CH + lk * 8;
    f32x4 acc[2] = {};
#pragma unroll
    for (int kb = 0; kb < 4; kb++) {
      sh8 rbh[2], rbl[2];
#pragma unroll
      for (int u = 0; u < 2; u++) {
        int o = (kb * 2 + u) * 32;
        rbh[u] = *(const sh8*)(B0h + o);
        rbl[u] = *(const sh8*)(B0l + o);
      }
#pragma unroll
      for (int u = 0; u < 2; u++) {
        int o2 = (kb * 2 + u) * 32 + lk * 8;
        sh8 a0h = *(const sh8*)&WH[lm * LROW + o2];
        sh8 a1h = *(const sh8*)&WH[(16 + lm) * LROW + o2];
        sh8 a0l = *(const sh8*)&WL[lm * LROW + o2];
        sh8 a1l = *(const sh8*)&WL[(16 + lm) * LROW + o2];
        acc[0] = MFMA(a0h, rbh[u], acc[0]);
        acc[0] = MFMA(a0h, rbl[u], acc[0]);
        acc[0] = MFMA(a0l, rbh[u], acc[0]);
        acc[1] = MFMA(a1h, rbh[u], acc[1]);
        acc[1] = MFMA(a1h, rbl[u], acc[1]);
        acc[1] = MFMA(a1l, rbh[u], acc[1]);
      }
    }
    int n = n0 + lm;
#pragma unroll
    for (int i = 0; i < 2; i++) {
      int d0 = dt * 32 + i * 16 + lk * 4;
      size_t off = ((size_t)b * NP + n) * DQ + d0;
      u16 h[4], lo[4];
#pragma unroll
      for (int r3 = 0; r3 < 4; r3++) {
        h[r3] = f2bf(acc[i][r3]);
        lo[r3] = f2bf(acc[i][r3] - bf2f(h[r3]));
      }
      if (mat == 0) {
        *(uint2*)&XQhi[off] = *(const uint2*)h;
        *(uint2*)&XQlo[off] = *(const uint2*)lo;
      } else {
        *(uint2*)&KLThi[off] = *(const uint2*)h;
        *(uint2*)&KLTlo[off] = *(const uint2*)lo;
      }
    }
  } else {
    int bi = blockIdx.x - 512;
    int ct = bi >> 6, b = bi & 63;
    u16* MT = WS;
    u16* WT = WS + 32 * LROW;
    {
      const u16* sM = Mb + (size_t)ct * 32 * CH;
      const u16* sW = Wlbf + (size_t)ct * 32 * CH;
      STAGE_W(MT, sM)
      STAGE_W(WT, sW)
    }
    __syncthreads();
    const u16* X0 = xThi + ((size_t)b * NP + wave * 32 + lm) * CH + lk * 8;
    const u16* X1 = X0 + 16 * CH;
    f32x4 awl[2][2] = {};
    f32x4 afp[2][2] = {};
#pragma unroll
    for (int kb = 0; kb < 2; kb++) {
      sh8 rx0[4], rx1[4];
#pragma unroll
      for (int u = 0; u < 4; u++) {
        int o = (kb * 4 + u) * 32;
        rx0[u] = *(const sh8*)(X0 + o);
        rx1[u] = *(const sh8*)(X1 + o);
      }
#pragma unroll
      for (int u = 0; u < 4; u++) {
        int o2 = (kb * 4 + u) * 32 + lk * 8;
        sh8 m0 = *(const sh8*)&MT[lm * LROW + o2];
        sh8 m1 = *(const sh8*)&MT[(16 + lm) * LROW + o2];
        sh8 w0 = *(const sh8*)&WT[lm * LROW + o2];
        sh8 w1 = *(const sh8*)&WT[(16 + lm) * LROW + o2];
        awl[0][0] = MFMA(m0, rx0[u], awl[0][0]);
        awl[0][1] = MFMA(m0, rx1[u], awl[0][1]);
        awl[1][0] = MFMA(m1, rx0[u], awl[1][0]);
        awl[1][1] = MFMA(m1, rx1[u], awl[1][1]);
        afp[0][0] = MFMA(w0, rx0[u], afp[0][0]);
        afp[0][1] = MFMA(w0, rx1[u], afp[0][1]);
        afp[1][0] = MFMA(w1, rx0[u], afp[1][0]);
        afp[1][1] = MFMA(w1, rx1[u], afp[1][1]);
      }
    }
#pragma unroll
    for (int i = 0; i < 2; i++)
#pragma unroll
      for (int j = 0; j < 2; j++) {
        int cl = ct * 32 + i * 16 + lk * 4;
        int n = wave * 32 + j * 16 + lm;
        uint2 up = *(const uint2*)&WlUP[((size_t)b * NP + n) * CH + cl];
        const u16* uph = (const u16*)&up;
#pragma unroll
        for (int r = 0; r < 4; r++) {
          WlU[((size_t)b * CH + cl + r) * NP + n] = f2bf(awl[i][j][r] + bf2f(uph[r]));
          Afp[((size_t)b * CH + cl + r) * NP + n] = afp[i][j][r];
        }
      }
  }
}

// ---------------------------------------------------------------------------
// Fused attention (512 blocks = 8 g-tiles of 16 rows x 64 b): energy MFMA +
// q1-MFMA + c1 + hw-trig bias + softmax + P^T bf16 + colsum partials (8/b).
__global__ __launch_bounds__(256) void k_att(
    const u16* __restrict__ XQhi, const u16* __restrict__ XQlo,
    const u16* __restrict__ KLThi, const u16* __restrict__ KLTlo,
    const u16* __restrict__ KP2hi, const u16* __restrict__ KP2lo,
    const u16* __restrict__ p1wT, const float* __restrict__ p1b,
    const float* __restrict__ AS, const float* __restrict__ beta_w, int layer,
    u16* __restrict__ PT, float* __restrict__ SCLp)
{
  __shared__ __align__(16) char smem[13056];
  int tid = threadIdx.x;
  int lane = tid & 63;
  int lm = lane & 15, lk = lane >> 4;
  int g8 = blockIdx.x & 7, b = blockIdx.x >> 3;
  int wave = tid >> 6;
  int n0 = g8 * 16;
  float* q1sh = (float*)smem;          // [16][66] = 4224B
  float* c1sh = q1sh + 16 * 66;        // [16]
  float* divs = c1sh + 16;             // [32]
  float* Esh  = divs + 32;             // [16][132] = 8448B
  if (tid < 32) divs[tid] = __expf(-(float)tid * DIV_STEP);
  float bw = beta_w[layer], obw = 1.0f - bw;
  // energy MFMA: wave = m-tile (32 m), n = 16 rows
  {
    int mt = wave;
    size_t arow = ((size_t)b * NP + mt * 32 + lm) * DQ + lk * 8;
    size_t brow = ((size_t)b * NP + n0 + lm) * DQ + lk * 8;
    const u16* L0h = KLThi + arow;
    const u16* L0l = KLTlo + arow;
    const u16* P0h = KP2hi + arow;
    const u16* P0l = KP2lo + arow;
    const u16* X0h = XQhi + brow;
    const u16* X0l = XQlo + brow;
    sh8 xh[2], xl[2], lh[2][2], llr[2][2], ph[2][2], pl[2][2];
#pragma unroll
    for (int ks = 0; ks < 2; ks++) {
      int o = ks * 32;
      xh[ks] = *(const sh8*)(X0h + o);
      xl[ks] = *(const sh8*)(X0l + o);
#pragma unroll
      for (int row = 0; row < 2; row++) {
        int o2 = row * 16 * DQ + o;
        lh[row][ks] = *(const sh8*)(L0h + o2);
        llr[row][ks] = *(const sh8*)(L0l + o2);
        ph[row][ks] = *(const sh8*)(P0h + o2);
        pl[row][ks] = *(const sh8*)(P0l + o2);
      }
    }
    f32x4 aL[2] = {};
    f32x4 aP[2] = {};
#pragma unroll
    for (int ks = 0; ks < 2; ks++) {
#pragma unroll
      for (int i = 0; i < 2; i++) {
        aL[i] = MFMA(lh[i][ks], xh[ks], aL[i]);
        aL[i] = MFMA(lh[i][ks], xl[ks], aL[i]);
        aL[i] = MFMA(llr[i][ks], xh[ks], aL[i]);
        aP[i] = MFMA(ph[i][ks], xh[ks], aP[i]);
        aP[i] = MFMA(ph[i][ks], xl[ks], aP[i]);
        aP[i] = MFMA(pl[i][ks], xh[ks], aP[i]);
      }
    }
#pragma unroll
    for (int i = 0; i < 2; i++) {
#pragma unroll
      for (int r = 0; r < 4; r++) {
        int mloc = mt * 32 + i * 16 + lk * 4 + r;
        Esh[lm * 132 + mloc] = bw * aL[i][r] + obw * aP[i][r];
      }
    }
  }
  // q1 via MFMA (waves 0,1): A = XQ rows n (16), B = p1wT rows d
  if (wave < 2) {
    const u16* A0 = XQhi + ((size_t)b * NP + n0 + lm) * DQ + lk * 8;
    const u16* B0 = p1wT + ((size_t)(wave * 32) + lm) * DQ + lk * 8;
    const u16* B1 = B0 + 16 * DQ;
    f32x4 q[2] = {};
#pragma unroll
    for (int ks = 0; ks < 2; ks++) {
      int o = ks * 32;
      sh8 a0 = *(const sh8*)(A0 + o);
      sh8 b0 = *(const sh8*)(B0 + o), b1 = *(const sh8*)(B1 + o);
      q[0] = MFMA(a0, b0, q[0]);
      q[1] = MFMA(a0, b1, q[1]);
    }
#pragma unroll
    for (int j = 0; j < 2; j++)
#pragma unroll
      for (int r = 0; r < 4; r++)
        q1sh[(lk * 4 + r) * 66 + wave * 32 + j * 16 + lm] = q[j][r];
  }
  // c1: 16 threads per row, 4 o each
  {
    int n = tid >> 4, o0 = (tid & 15) * 4;
    const u16* xs = XQhi + ((size_t)b * NP + n0 + n) * DQ + o0;
    uint2 w0 = *(const uint2*)xs;
    const u16* hh = (const u16*)&w0;
    float s = 0.0f;
#pragma unroll
    for (int k = 0; k < 4; k++) s = fmaf(bf2f(hh[k]), p1b[o0 + k], s);
    s += __shfl_xor(s, 1);
    s += __shfl_xor(s, 2);
    s += __shfl_xor(s, 4);
    s += __shfl_xor(s, 8);
    if ((tid & 15) == 0) c1sh[n] = s;
  }
  __syncthreads();
  // bias + softmax: 16 threads per row, 8 m each
  {
    int n = tid >> 4, mc = (tid & 15) * 8;
    size_t asrow = ((size_t)b * NP + n0 + n) * NP + mc;
    float idxv[8], bias[8];
    float c1v = c1sh[n];
#pragma unroll
    for (int k4 = 0; k4 < 2; k4++) {
      float4 a4 = *(const float4*)&AS[asrow + k4 * 4];
      idxv[k4 * 4 + 0] = a4.x * ANG_REV;
      idxv[k4 * 4 + 1] = a4.y * ANG_REV;
      idxv[k4 * 4 + 2] = a4.z * ANG_REV;
      idxv[k4 * 4 + 3] = a4.w * ANG_REV;
    }
#pragma unroll
    for (int k = 0; k < 8; k++) bias[k] = c1v;
    for (int j = 0; j < 32; j++) {
      float dv = divs[j];
      float qs = q1sh[n * 66 + 2 * j], qc = q1sh[n * 66 + 2 * j + 1];
#pragma unroll
      for (int k = 0; k < 8; k++) {
        float rev = idxv[k] * dv;   // |rev| <= 0.61 revolutions
        bias[k] = fmaf(qs, hw_sin(rev), bias[k]);
        bias[k] = fmaf(qc, hw_cos(rev), bias[k]);
      }
    }
    float ev[8], mx = -1e30f;
#pragma unroll
    for (int k = 0; k < 8; k++) {
      ev[k] = Esh[n * 132 + mc + k] + bw * bias[k];
      mx = fmaxf(mx, ev[k]);
    }
    mx = fmaxf(mx, __shfl_xor(mx, 1));
    mx = fmaxf(mx, __shfl_xor(mx, 2));
    mx = fmaxf(mx, __shfl_xor(mx, 4));
    mx = fmaxf(mx, __shfl_xor(mx, 8));
    float s = 0.0f;
#pragma unroll
    for (int k = 0; k < 8; k++) {
      ev[k] = __expf(ev[k] - mx);
      s += ev[k];
    }
    s += __shfl_xor(s, 1);
    s += __shfl_xor(s, 2);
    s += __shfl_xor(s, 4);
    s += __shfl_xor(s, 8);
    float inv = 1.0f / s;
#pragma unroll
    for (int k = 0; k < 8; k++) Esh[n * 132 + mc + k] = ev[k] * inv;
  }
  __syncthreads();
  // P^T bf16 (8 n per thread) + colsum partial
  {
    int m = tid >> 1, nc = (tid & 1) * 8;
    float s = 0.0f;
    u16 tmp[8];
#pragma unroll
    for (int k = 0; k < 8; k++) {
      float v = Esh[(nc + k) * 132 + m];
      s += v;
      tmp[k] = f2bf(v);
    }
    u16* dst = PT + ((size_t)b * NP + m) * NP + n0 + nc;
    *(uint4*)&dst[0] = *(const uint4*)&tmp[0];
    s += __shfl_xor(s, 1);
    if ((tid & 1) == 0) SCLp[((size_t)b * 8 + g8) * NP + m] = s;
  }
}

// ---------------------------------------------------------------------------
// Value epilogue (512 blocks = 8ct x 64b): stage WlU tile -> LDS, P-GEMM
// (K=128), out = x + gelu(BN(Afp - acc2*scl + bl)); writes next xT plane.
__global__ __launch_bounds__(256) void k_h5(
    const u16* __restrict__ WlU, const u16* __restrict__ PT,
    const float* __restrict__ SCLp, const float* __restrict__ Afp,
    const float* __restrict__ bl, const float* __restrict__ bng,
    const float* __restrict__ bnb, const float* __restrict__ xsrc, int xbs,
    float* __restrict__ out, int layer,
    u16* __restrict__ xThi_o, u16* __restrict__ xTlo_o)
{
  __shared__ __align__(16) u16 WS2[32 * LROW2];
  int ct = blockIdx.x >> 6, b = blockIdx.x & 63;
  int tid = threadIdx.x, lane = tid & 63, wave = tid >> 6;
  int lm = lane & 15, lk = lane >> 4;
  {
    const u16* src = WlU + ((size_t)b * CH + ct * 32) * NP;
#pragma unroll
    for (int it = 0; it < 2; it++) {
      int idx = tid + it * 256, row = idx >> 4, chq = idx & 15;
      *(uint4*)&WS2[row * LROW2 + chq * 8] = *(const uint4*)(src + row * NP + chq * 8);
    }
  }
  __syncthreads();
  const u16* B0 = PT + ((size_t)b * NP + wave * 32 + lm) * NP + lk * 8;
  const u16* B1 = B0 + 16 * NP;
  sh8 rB0[4], rB1[4];
#pragma unroll
  for (int ks = 0; ks < 4; ks++) {
    int o = ks * 32;
    rB0[ks] = *(const sh8*)(B0 + o);
    rB1[ks] = *(const sh8*)(B1 + o);
  }
  f32x4 a00 = {}, a01 = {}, a10 = {}, a11 = {};
#pragma unroll
  for (int ks = 0; ks < 4; ks++) {
    int o2 = ks * 32 + lk * 8;
    sh8 w0 = *(const sh8*)&WS2[lm * LROW2 + o2];
    sh8 w1 = *(const sh8*)&WS2[(16 + lm) * LROW2 + o2];
    a00 = MFMA(w0, rB0[ks], a00);
    a01 = MFMA(w0, rB1[ks], a01);
    a10 = MFMA(w1, rB0[ks], a10);
    a11 = MFMA(w1, rB1[ks], a11);
  }
  f32x4 acc2[2][2] = {{a00, a01}, {a10, a11}};
  const float rbn = 0.999995000037499687f;  // 1/sqrt(1+1e-5)
#pragma unroll
  for (int i = 0; i < 2; i++)
#pragma unroll
    for (int j = 0; j < 2; j++) {
      int m = wave * 32 + j * 16 + lm;
      int cq = ct * 32 + i * 16 + lk * 4;
      const float* sp = SCLp + (size_t)b * 8 * NP + m;
      float scl = 1.0f / (1e-12f + sp[0] + sp[NP] + sp[2 * NP] + sp[3 * NP] +
                          sp[4 * NP] + sp[5 * NP] + sp[6 * NP] + sp[7 * NP]);
      u16 hh[4], llv[4];
#pragma unroll
      for (int r = 0; r < 4; r++) {
        int c = cq + r;
        float a = Afp[((size_t)b * CH + c) * NP + m];
        float h = a - acc2[i][j][r] * scl + bl[c];
        h = h * rbn * bng[c] + bnb[c];
        float gg = 0.5f * h * (1.0f + erff(h * 0.70710678118654752440f));
        float ov = xsrc[(size_t)b * xbs + (size_t)c * NP + m] + gg;
        out[((size_t)b * 4 * CH + (size_t)layer * CH + c) * NP + m] = ov;
        hh[r] = f2bf(ov);
        llv[r] = f2bf(ov - bf2f(hh[r]));
      }
      size_t xoff = ((size_t)b * NP + m) * CH + cq;
      *(uint2*)&xThi_o[xoff] = *(const uint2*)hh;
      *(uint2*)&xTlo_o[xoff] = *(const uint2*)llv;
    }
}

// ---------------------------------------------------------------------------
extern "C" void kernel_launch(void* const* d_in, const int* in_sizes, int n_in,
                              void* d_out, int out_size, void* d_ws, size_t ws_size,
                              hipStream_t stream)
{
  (void)in_sizes; (void)n_in; (void)out_size; (void)ws_size;
  const float* lrf     = (const float*)d_in[0];
  const float* pca     = (const float*)d_in[1];
  const float* a_self  = (const float*)d_in[2];
  const float* a_cross = (const float*)d_in[3];
  const float* Wq  = (const float*)d_in[4];
  const float* Wk  = (const float*)d_in[5];
  const float* Wv  = (const float*)d_in[6];
  const float* Wvp = (const float*)d_in[7];
  const float* Wl  = (const float*)d_in[8];
  const float* bl  = (const float*)d_in[9];
  const float* bng = (const float*)d_in[10];
  const float* bnb = (const float*)d_in[11];
  const float* p1w = (const float*)d_in[12];
  const float* p1b = (const float*)d_in[13];
  const float* p2w = (const float*)d_in[14];
  const float* p2b = (const float*)d_in[15];
  const float* beta_x = (const float*)d_in[16];
  const float* beta_w = (const float*)d_in[17];
  float* out = (float*)d_out;
  float* ws  = (float*)d_ws;

  // ---- workspace carve ----
  const size_t QKN = (size_t)BB * NP * DQ;        // 524288
  const size_t ENN = (size_t)BB * NP * NP;        // 1048576
  const size_t XCN = (size_t)BB * NP * CH;        // 2097152

  float* SCLp = ws;
  float* Afp  = SCLp + (size_t)BB * 8 * NP;
  u16* up = (u16*)(Afp + (size_t)BB * CH * NP);
  u16* xThiA = up;  up += XCN;   // double-buffered x^T planes
  u16* xTloA = up;  up += XCN;
  u16* xThiB = up;  up += XCN;
  u16* xTloB = up;  up += XCN;
  u16* pThi = up;   up += XCN;
  u16* pTlo = up;   up += XCN;
  u16* XQhi = up;   up += QKN;
  u16* XQlo = up;   up += QKN;
  u16* KLThi = up;  up += QKN;
  u16* KLTlo = up;  up += QKN;
  u16* KP2hiA = up; up += (size_t)NLAYERS * QKN;
  u16* KP2loA = up; up += (size_t)NLAYERS * QKN;
  u16* WlUPA = up;  up += (size_t)NLAYERS * XCN;
  u16* WlUb = up;   up += XCN;
  u16* PTbf = up;   up += ENN;
  u16* Wlbf = up;   up += (size_t)NLAYERS * CH * CH;
  u16* WvT = up;    up += (size_t)NLAYERS * CH * CH;
  u16* WvpT = up;   up += (size_t)NLAYERS * CH * CH;
  u16* Mb = up;     up += (size_t)NLAYERS * CH * CH;
  u16* M2b = up;    up += (size_t)NLAYERS * CH * CH;
  u16* Wqhi = up;   up += (size_t)NLAYERS * DQ * CH;
  u16* Wqlo = up;   up += (size_t)NLAYERS * DQ * CH;
  u16* Wkhi = up;   up += (size_t)NLAYERS * DQ * CH;
  u16* Wklo = up;   up += (size_t)NLAYERS * DQ * CH;
  u16* p1wT = up;   up += (size_t)NLAYERS * DQ * DQ;
  u16* p2wbf = up;  up += (size_t)NLAYERS * DQ * DQ;
  u16* emb2bf = up; up += QKN;

  // ---- pre-loop (3 launches) ----
  k_init<<<dim3(2568), 256, 0, stream>>>(
      Wv, Wvp, Wl, Wq, Wk, p1w, p2w, pca, lrf, a_cross,
      Wlbf, Wqhi, Wqlo, Wkhi, Wklo, p1wT, p2wbf,
      pThi, pTlo, xThiA, xTloA, WvT, WvpT, emb2bf);
  k_mm<<<dim3(128), 256, 0, stream>>>(WvT, WvpT, Wlbf, beta_x, Mb, M2b);
  k_pre2<<<dim3(2560), 256, 0, stream>>>(
      pThi, pTlo, Wqhi, Wqlo, M2b, p2wbf, emb2bf, p2b,
      KP2hiA, KP2loA, WlUPA);

  // ---- layer loop (3 launches each) ----
  for (int l = 0; l < NLAYERS; l++) {
    const float* xsrc = (l == 0) ? lrf : (out + (size_t)(l - 1) * CH * NP);
    int xbs = (l == 0) ? CH * NP : 4 * CH * NP;
    u16* xhi_in  = (l & 1) ? xThiB : xThiA;
    u16* xlo_in  = (l & 1) ? xTloB : xTloA;
    u16* xhi_out = (l & 1) ? xThiA : xThiB;
    u16* xlo_out = (l & 1) ? xTloA : xTloB;
    k_qkh<<<dim3(1024), 256, 0, stream>>>(
        xhi_in, xlo_in,
        Wqhi + (size_t)l * DQ * CH, Wqlo + (size_t)l * DQ * CH,
        Wkhi + (size_t)l * DQ * CH, Wklo + (size_t)l * DQ * CH,
        Mb + (size_t)l * CH * CH, Wlbf + (size_t)l * CH * CH,
        WlUPA + (size_t)l * XCN,
        XQhi, XQlo, KLThi, KLTlo, WlUb, Afp);
    k_att<<<dim3(512), 256, 0, stream>>>(
        XQhi, XQlo, KLThi, KLTlo,
        KP2hiA + (size_t)l * QKN, KP2loA + (size_t)l * QKN,
        p1wT + (size_t)l * DQ * DQ, p1b + (size_t)l * DQ,
        a_self, beta_w, l, PTbf, SCLp);
    k_h5<<<dim3(512), 256, 0, stream>>>(
        WlUb, PTbf, SCLp, Afp, bl + (size_t)l * CH, bng + (size_t)l * CH,
        bnb + (size_t)l * CH, xsrc, xbs, out, l, xhi_out, xlo_out);
  }
}

// Round 17
// 203.751 us; speedup vs baseline: 1.0722x; 1.0722x over previous
//
#include <hip/hip_runtime.h>
#include <cstdint>
#include <cstddef>

// Round 17: REVERT to round-15 configuration (best measured: 204.5 us,
// absmax 0.094). Round-16's hoist+split regressed to 218 us (added 6MB/layer
// WlU/Afp round-trips + doubled redundant K loads in split k_att). R15 config:
// 3 pre-launches (k_init, k_mm, k_pre2) + 4 layers x {k_qk 512, k_att 256,
// k_h4 512}.

#define BB 64      // batch
#define CH 256     // channels
#define NP 128     // points
#define DQ 64      // q/k dim
#define NLAYERS 4

#define ANG_REV    0.6079271018540267f   // (180/(pi*15)) / (2*pi)
#define DIV_STEP   0.28782313662425575f  // ln(10000)/32

#define LROW 264   // padded LDS row stride (u16) for 256-wide tiles

typedef unsigned short u16;
typedef __attribute__((ext_vector_type(8))) short sh8;   // 8 bf16 = 4 VGPR
typedef __attribute__((ext_vector_type(4))) float f32x4; // MFMA C/D
#define MFMA(a, b, c) __builtin_amdgcn_mfma_f32_16x16x32_bf16(a, b, c, 0, 0, 0)

static __device__ __forceinline__ u16 f2bf(float x) {
  unsigned u = __float_as_uint(x);
  return (u16)((u + 0x7FFFu + ((u >> 16) & 1u)) >> 16);
}
static __device__ __forceinline__ float bf2f(u16 h) {
  return __uint_as_float(((unsigned)h) << 16);
}
// HW trig, input in REVOLUTIONS (valid: our args bounded by +-0.61 rev)
static __device__ __forceinline__ float hw_sin(float rev) {
  float r;
  asm("v_sin_f32 %0, %1" : "=v"(r) : "v"(rev));
  return r;
}
static __device__ __forceinline__ float hw_cos(float rev) {
  float r;
  asm("v_cos_f32 %0, %1" : "=v"(r) : "v"(rev));
  return r;
}

// ---------------------------------------------------------------------------
// Merged init (2568 blocks): weight cvts, transposes, emb2 bf16.
__global__ __launch_bounds__(256) void k_init(
    const float* __restrict__ Wv, const float* __restrict__ Wvp,
    const float* __restrict__ Wl, const float* __restrict__ Wq,
    const float* __restrict__ Wk, const float* __restrict__ p1w,
    const float* __restrict__ p2w, const float* __restrict__ pca,
    const float* __restrict__ lrf, const float* __restrict__ ac,
    u16* __restrict__ Wlbf, u16* __restrict__ Wqhi, u16* __restrict__ Wqlo,
    u16* __restrict__ Wkhi, u16* __restrict__ Wklo, u16* __restrict__ p1wT,
    u16* __restrict__ p2wbf, u16* __restrict__ pThi, u16* __restrict__ pTlo,
    u16* __restrict__ xThi, u16* __restrict__ xTlo,
    u16* __restrict__ WvT, u16* __restrict__ WvpT, u16* __restrict__ emb2bf)
{
  __shared__ __align__(16) float tl[64 * 65];
  int blk = blockIdx.x, tid = threadIdx.x;
  if (blk < 256) {
    int i = (blk * 256 + tid) * 4;
    float4 v = *(const float4*)(Wl + i);
    u16 o[4] = {f2bf(v.x), f2bf(v.y), f2bf(v.z), f2bf(v.w)};
    *(uint2*)(Wlbf + i) = *(const uint2*)o;
  } else if (blk < 384) {
    int bb = blk - 256;
    const float* s = (bb < 64) ? Wq : Wk;
    u16* dh = (bb < 64) ? Wqhi : Wkhi;
    u16* dl = (bb < 64) ? Wqlo : Wklo;
    int i = ((bb & 63) * 256 + tid) * 4;
    float4 v = *(const float4*)(s + i);
    float vv[4] = {v.x, v.y, v.z, v.w};
    u16 h[4], l[4];
#pragma unroll
    for (int r = 0; r < 4; r++) {
      h[r] = f2bf(vv[r]);
      l[r] = f2bf(vv[r] - bf2f(h[r]));
    }
    *(uint2*)(dh + i) = *(const uint2*)h;
    *(uint2*)(dl + i) = *(const uint2*)l;
  } else if (blk < 388) {
    int l = blk - 384;
    const float* src = p1w + (size_t)l * DQ * DQ;
    u16* dst = p1wT + (size_t)l * DQ * DQ;
#pragma unroll
    for (int i = 0; i < 16; i++) {
      int idx = tid + i * 256;
      int dd = idx >> 6, oo = idx & 63;
      dst[idx] = f2bf(src[oo * DQ + dd]);
    }
  } else if (blk < 392) {
    int l = blk - 388;
    const float* src = p2w + (size_t)l * DQ * DQ;
    u16* dst = p2wbf + (size_t)l * DQ * DQ;
#pragma unroll
    for (int i = 0; i < 16; i++) {
      int idx = tid + i * 256;
      dst[idx] = f2bf(src[idx]);
    }
  } else if (blk < 1416) {
    int bi = blk - 392;
    int nt = bi & 1, y = (bi >> 1) & 7, b = bi >> 4;
    int ct = y & 3, is_lrf = y >> 2;
    const float* x = is_lrf ? lrf : pca;
    u16* hiT = is_lrf ? xThi : pThi;
    u16* loT = is_lrf ? xTlo : pTlo;
    {
      int col = tid & 63, rq = tid >> 6;
      const float* src = x + (size_t)b * CH * NP + (size_t)(ct * 64) * NP + nt * 64;
#pragma unroll
      for (int i = 0; i < 16; i++) {
        int c = rq + i * 4;
        tl[col * 65 + c] = src[(size_t)c * NP + col];
      }
    }
    __syncthreads();
    {
      int cloc = tid & 63, nq = tid >> 6;
#pragma unroll
      for (int i = 0; i < 16; i++) {
        int n = nq + i * 4;
        float v = tl[n * 65 + cloc];
        u16 h = f2bf(v);
        u16 l = f2bf(v - bf2f(h));
        size_t off = ((size_t)b * NP + nt * 64 + n) * CH + ct * 64 + cloc;
        hiT[off] = h;
        loT[off] = l;
      }
    }
  } else if (blk < 1544) {
    int bi = blk - 1416;
    int mat = bi >> 4, t = bi & 15;
    int l = mat & 3;
    const float* src = ((mat < 4) ? Wv : Wvp) + (size_t)l * CH * CH;
    u16* dst = ((mat < 4) ? WvT : WvpT) + (size_t)l * CH * CH;
    int tr = t >> 2, tc = t & 3;
    {
      int col = tid & 63, rq = tid >> 6;
#pragma unroll
      for (int i = 0; i < 16; i++) {
        int co = rq + i * 4;
        tl[col * 65 + co] = src[(size_t)(tr * 64 + co) * CH + tc * 64 + col];
      }
    }
    __syncthreads();
    {
      int cloc = tid & 63, nq = tid >> 6;
#pragma unroll
      for (int i = 0; i < 16; i++) {
        int n = nq + i * 4;
        dst[(size_t)(tc * 64 + n) * CH + tr * 64 + cloc] = f2bf(tl[n * 65 + cloc]);
      }
    }
  } else {
    int bi = blk - 1544;
    int row0 = bi * 8;
    int r = tid >> 5, j = tid & 31;
    int row = row0 + r;
    float a = ac[row];
    float rev = a * ANG_REV * __expf(-(float)j * DIV_STEP);
    emb2bf[(size_t)row * DQ + 2 * j] = f2bf(hw_sin(rev));
    emb2bf[(size_t)row * DQ + 2 * j + 1] = f2bf(hw_cos(rev));
  }
}

// ---------------------------------------------------------------------------
// M[l] = bx*Wl@Wv, M2[l] = (1-bx)*Wl@Wvp, bf16 [c'][c] (k=c contiguous).
__global__ __launch_bounds__(256) void k_mm(
    const u16* __restrict__ WvT, const u16* __restrict__ WvpT,
    const u16* __restrict__ Wlbf, const float* __restrict__ beta_x,
    u16* __restrict__ Mb, u16* __restrict__ M2b)
{
  int tid = threadIdx.x, lane = tid & 63;
  int lm = lane & 15, lk = lane >> 4;
  int tt = blockIdx.x * 4 + (tid >> 6);
  int which = tt >> 8, rest = tt & 255;
  int l = rest >> 6, t = rest & 63;
  int tcp = t >> 3, tcc = t & 7;
  const u16* WT = (which ? WvpT : WvT) + (size_t)l * CH * CH;
  const u16* A0 = WT + ((size_t)(tcc * 32) + lm) * CH + lk * 8;
  const u16* A1 = A0 + 16 * CH;
  const u16* B0 = Wlbf + (size_t)l * CH * CH + ((size_t)(tcp * 32) + lm) * CH + lk * 8;
  const u16* B1 = B0 + 16 * CH;
  f32x4 a00 = {}, a01 = {}, a10 = {}, a11 = {};
#pragma unroll
  for (int ks = 0; ks < 8; ks++) {
    int o = ks * 32;
    sh8 a0 = *(const sh8*)(A0 + o), a1 = *(const sh8*)(A1 + o);
    sh8 b0 = *(const sh8*)(B0 + o), b1 = *(const sh8*)(B1 + o);
    a00 = MFMA(a0, b0, a00);
    a01 = MFMA(a0, b1, a01);
    a10 = MFMA(a1, b0, a10);
    a11 = MFMA(a1, b1, a11);
  }
  float bx = beta_x[l];
  float sc = which ? (1.0f - bx) : bx;
  u16* out = (which ? M2b : Mb) + (size_t)l * CH * CH;
  f32x4 acc[2][2] = {{a00, a01}, {a10, a11}};
#pragma unroll
  for (int i = 0; i < 2; i++)
#pragma unroll
    for (int j = 0; j < 2; j++) {
      int c0 = tcc * 32 + i * 16 + lk * 4;
      int cp = tcp * 32 + j * 16 + lm;
      u16 ov[4];
#pragma unroll
      for (int r = 0; r < 4; r++) ov[r] = f2bf(sc * acc[i][j][r]);
      *(uint2*)&out[(size_t)cp * CH + c0] = *(const uint2*)ov;
    }
}

// ---------------------------------------------------------------------------
#define STAGE_W(dst, src)                                                    \
  _Pragma("unroll")                                                          \
  for (int it = 0; it < 4; it++) {                                           \
    int idx = threadIdx.x + it * 256, row = idx >> 5, ch = idx & 31;         \
    *(uint4*)&dst[row * LROW + ch * 8] =                                     \
        *(const uint4*)(src + row * 256 + ch * 8);                           \
  }

// ---------------------------------------------------------------------------
// [0,512): KP2A[l] = split(Wq[l]@pca + emb2@p2w[l]^T + p2b[l]);
// [512,2560): WlUPA[l][b][n][c'] = bf(M2[l]@pca).
__global__ __launch_bounds__(256) void k_pre2(
    const u16* __restrict__ pThi, const u16* __restrict__ pTlo,
    const u16* __restrict__ Wqhi, const u16* __restrict__ Wqlo,
    const u16* __restrict__ M2b, const u16* __restrict__ p2wbf,
    const u16* __restrict__ emb2bf, const float* __restrict__ p2b,
    u16* __restrict__ KP2hiA, u16* __restrict__ KP2loA, u16* __restrict__ WlUPA)
{
  __shared__ __align__(16) u16 WS[2 * 32 * LROW];
  int tid = threadIdx.x, lane = tid & 63;
  int lm = lane & 15, lk = lane >> 4;
  if (blockIdx.x < 512) {
    int bi = blockIdx.x;
    int l = bi >> 7, rest = bi & 127;
    int dt = rest >> 6, b = rest & 63;
    int nt = tid >> 6;
    u16* WH = WS;
    u16* WL = WS + 32 * LROW;
    {
      const u16* sH = Wqhi + (size_t)l * DQ * CH + (size_t)dt * 32 * CH;
      const u16* sL = Wqlo + (size_t)l * DQ * CH + (size_t)dt * 32 * CH;
      STAGE_W(WH, sH)
      STAGE_W(WL, sL)
    }
    __syncthreads();
    const u16* B0h = pThi + ((size_t)b * NP + nt * 32 + lm) * CH + lk * 8;
    const u16* B1h = B0h + 16 * CH;
    const u16* B0l = pTlo + ((size_t)b * NP + nt * 32 + lm) * CH + lk * 8;
    const u16* B1l = B0l + 16 * CH;
    f32x4 acc[2][2] = {};
#pragma unroll
    for (int kb = 0; kb < 4; kb++) {
      sh8 rb0h[2], rb1h[2], rb0l[2], rb1l[2];
#pragma unroll
      for (int u = 0; u < 2; u++) {
        int o = (kb * 2 + u) * 32;
        rb0h[u] = *(const sh8*)(B0h + o); rb1h[u] = *(const sh8*)(B1h + o);
        rb0l[u] = *(const sh8*)(B0l + o); rb1l[u] = *(const sh8*)(B1l + o);
      }
#pragma unroll
      for (int u = 0; u < 2; u++) {
        int o2 = (kb * 2 + u) * 32 + lk * 8;
        sh8 a0h = *(const sh8*)&WH[lm * LROW + o2];
        sh8 a1h = *(const sh8*)&WH[(16 + lm) * LROW + o2];
        sh8 a0l = *(const sh8*)&WL[lm * LROW + o2];
        sh8 a1l = *(const sh8*)&WL[(16 + lm) * LROW + o2];
        acc[0][0] = MFMA(a0h, rb0h[u], acc[0][0]);
        acc[0][0] = MFMA(a0h, rb0l[u], acc[0][0]);
        acc[0][0] = MFMA(a0l, rb0h[u], acc[0][0]);
        acc[0][1] = MFMA(a0h, rb1h[u], acc[0][1]);
        acc[0][1] = MFMA(a0h, rb1l[u], acc[0][1]);
        acc[0][1] = MFMA(a0l, rb1h[u], acc[0][1]);
        acc[1][0] = MFMA(a1h, rb0h[u], acc[1][0]);
        acc[1][0] = MFMA(a1h, rb0l[u], acc[1][0]);
        acc[1][0] = MFMA(a1l, rb0h[u], acc[1][0]);
        acc[1][1] = MFMA(a1h, rb1h[u], acc[1][1]);
        acc[1][1] = MFMA(a1h, rb1l[u], acc[1][1]);
        acc[1][1] = MFMA(a1l, rb1h[u], acc[1][1]);
      }
    }
    {
      const u16* A20 = p2wbf + (size_t)l * DQ * DQ + ((size_t)(dt * 32) + lm) * DQ + lk * 8;
      const u16* A21 = A20 + 16 * DQ;
      const u16* B20 = emb2bf + ((size_t)b * NP + nt * 32 + lm) * DQ + lk * 8;
      const u16* B21 = B20 + 16 * DQ;
#pragma unroll
      for (int ks = 0; ks < 2; ks++) {
        int o = ks * 32;
        sh8 a0 = *(const sh8*)(A20 + o), a1 = *(const sh8*)(A21 + o);
        sh8 b0 = *(const sh8*)(B20 + o), b1 = *(const sh8*)(B21 + o);
        acc[0][0] = MFMA(a0, b0, acc[0][0]);
        acc[0][1] = MFMA(a0, b1, acc[0][1]);
        acc[1][0] = MFMA(a1, b0, acc[1][0]);
        acc[1][1] = MFMA(a1, b1, acc[1][1]);
      }
    }
#pragma unroll
    for (int i = 0; i < 2; i++)
#pragma unroll
      for (int j = 0; j < 2; j++) {
        int n = nt * 32 + j * 16 + lm;
        int d0 = dt * 32 + i * 16 + lk * 4;
        size_t off = (((size_t)l * BB + b) * NP + n) * DQ + d0;
        f32x4 v = acc[i][j];
        u16 h[4], lo[4];
#pragma unroll
        for (int r2 = 0; r2 < 4; r2++) {
          float vv = v[r2] + p2b[l * DQ + d0 + r2];
          h[r2] = f2bf(vv);
          lo[r2] = f2bf(vv - bf2f(h[r2]));
        }
        *(uint2*)&KP2hiA[off] = *(const uint2*)h;
        *(uint2*)&KP2loA[off] = *(const uint2*)lo;
      }
  } else {
    int bi = blockIdx.x - 512;
    int l = bi >> 9, rest = bi & 511;
    int ct = rest >> 6, b = rest & 63;
    int nt = tid >> 6;
    {
      const u16* sH = M2b + (size_t)l * CH * CH + (size_t)ct * 32 * CH;
      STAGE_W(WS, sH)
    }
    __syncthreads();
    const u16* X0 = pThi + ((size_t)b * NP + nt * 32 + lm) * CH + lk * 8;
    const u16* X1 = X0 + 16 * CH;
    f32x4 a00 = {}, a01 = {}, a10 = {}, a11 = {};
#pragma unroll
    for (int kb = 0; kb < 2; kb++) {
      sh8 rx0[4], rx1[4];
#pragma unroll
      for (int u = 0; u < 4; u++) {
        int o = (kb * 4 + u) * 32;
        rx0[u] = *(const sh8*)(X0 + o); rx1[u] = *(const sh8*)(X1 + o);
      }
#pragma unroll
      for (int u = 0; u < 4; u++) {
        int o2 = (kb * 4 + u) * 32 + lk * 8;
        sh8 w0 = *(const sh8*)&WS[lm * LROW + o2];
        sh8 w1 = *(const sh8*)&WS[(16 + lm) * LROW + o2];
        a00 = MFMA(w0, rx0[u], a00);
        a01 = MFMA(w0, rx1[u], a01);
        a10 = MFMA(w1, rx0[u], a10);
        a11 = MFMA(w1, rx1[u], a11);
      }
    }
    f32x4 acc[2][2] = {{a00, a01}, {a10, a11}};
#pragma unroll
    for (int i = 0; i < 2; i++)
#pragma unroll
      for (int j = 0; j < 2; j++) {
        int c0 = ct * 32 + i * 16 + lk * 4;
        int n = nt * 32 + j * 16 + lm;
        u16 ov[4];
#pragma unroll
        for (int r2 = 0; r2 < 4; r2++) ov[r2] = f2bf(acc[i][j][r2]);
        *(uint2*)&WlUPA[(((size_t)l * BB + b) * NP + n) * CH + c0] = *(const uint2*)ov;
      }
  }
}

// ---------------------------------------------------------------------------
// Per-layer QK projections, 512 blocks = 2mat x 2dt x 64b x 2nh; each wave
// handles a 16-row n-tile (2 waves/SIMD occupancy).
__global__ __launch_bounds__(256) void k_qk(
    const u16* __restrict__ xThi, const u16* __restrict__ xTlo,
    const u16* __restrict__ Wqhi, const u16* __restrict__ Wqlo,
    const u16* __restrict__ Wkhi, const u16* __restrict__ Wklo,
    u16* __restrict__ XQhi, u16* __restrict__ XQlo,
    u16* __restrict__ KLThi, u16* __restrict__ KLTlo)
{
  __shared__ __align__(16) u16 WS[2 * 32 * LROW];
  int tid = threadIdx.x, lane = tid & 63, wave = tid >> 6;
  int lm = lane & 15, lk = lane >> 4;
  int bi = blockIdx.x;
  int mat = bi >> 8, r = bi & 255;
  int dt = r >> 7, r2 = r & 127;
  int nh = r2 >> 6, b = r2 & 63;
  u16* WH = WS;
  u16* WL = WS + 32 * LROW;
  {
    const u16* sH = (mat ? Wkhi : Wqhi) + (size_t)dt * 32 * CH;
    const u16* sL = (mat ? Wklo : Wqlo) + (size_t)dt * 32 * CH;
    STAGE_W(WH, sH)
    STAGE_W(WL, sL)
  }
  __syncthreads();
  int n0 = nh * 64 + wave * 16;
  const u16* B0h = xThi + ((size_t)b * NP + n0 + lm) * CH + lk * 8;
  const u16* B0l = xTlo + ((size_t)b * NP + n0 + lm) * CH + lk * 8;
  f32x4 acc[2] = {};
#pragma unroll
  for (int kb = 0; kb < 4; kb++) {
    sh8 rbh[2], rbl[2];
#pragma unroll
    for (int u = 0; u < 2; u++) {
      int o = (kb * 2 + u) * 32;
      rbh[u] = *(const sh8*)(B0h + o);
      rbl[u] = *(const sh8*)(B0l + o);
    }
#pragma unroll
    for (int u = 0; u < 2; u++) {
      int o2 = (kb * 2 + u) * 32 + lk * 8;
      sh8 a0h = *(const sh8*)&WH[lm * LROW + o2];
      sh8 a1h = *(const sh8*)&WH[(16 + lm) * LROW + o2];
      sh8 a0l = *(const sh8*)&WL[lm * LROW + o2];
      sh8 a1l = *(const sh8*)&WL[(16 + lm) * LROW + o2];
      acc[0] = MFMA(a0h, rbh[u], acc[0]);
      acc[0] = MFMA(a0h, rbl[u], acc[0]);
      acc[0] = MFMA(a0l, rbh[u], acc[0]);
      acc[1] = MFMA(a1h, rbh[u], acc[1]);
      acc[1] = MFMA(a1h, rbl[u], acc[1]);
      acc[1] = MFMA(a1l, rbh[u], acc[1]);
    }
  }
  int n = n0 + lm;
#pragma unroll
  for (int i = 0; i < 2; i++) {
    int d0 = dt * 32 + i * 16 + lk * 4;
    size_t off = ((size_t)b * NP + n) * DQ + d0;
    u16 h[4], lo[4];
#pragma unroll
    for (int r3 = 0; r3 < 4; r3++) {
      h[r3] = f2bf(acc[i][r3]);
      lo[r3] = f2bf(acc[i][r3] - bf2f(h[r3]));
    }
    if (mat == 0) {
      *(uint2*)&XQhi[off] = *(const uint2*)h;
      *(uint2*)&XQlo[off] = *(const uint2*)lo;
    } else {
      *(uint2*)&KLThi[off] = *(const uint2*)h;
      *(uint2*)&KLTlo[off] = *(const uint2*)lo;
    }
  }
}

// ---------------------------------------------------------------------------
// Fused attention (256 blocks): energy MFMA + q1-MFMA + c1 + hw-trig bias +
// softmax + P^T bf16 + colsum partials.
__global__ __launch_bounds__(256) void k_att(
    const u16* __restrict__ XQhi, const u16* __restrict__ XQlo,
    const u16* __restrict__ KLThi, const u16* __restrict__ KLTlo,
    const u16* __restrict__ KP2hi, const u16* __restrict__ KP2lo,
    const u16* __restrict__ p1wT, const float* __restrict__ p1b,
    const float* __restrict__ AS, const float* __restrict__ beta_w, int layer,
    u16* __restrict__ PT, float* __restrict__ SCLp)
{
  __shared__ __align__(16) char smem[25856];
  int tid = threadIdx.x;
  int lane = tid & 63;
  int lm = lane & 15, lk = lane >> 4;
  int g = blockIdx.x & 3, b = blockIdx.x >> 2;
  int wave = tid >> 6;
  float* q1sh = (float*)smem;          // [32][66]
  float* c1sh = q1sh + 32 * 66;        // [32]
  float* divs = c1sh + 32;             // [32]
  float* Esh  = divs + 32;             // [32][132]
  if (tid < 32) divs[tid] = __expf(-(float)tid * DIV_STEP);
  float bw = beta_w[layer], obw = 1.0f - bw;
  {
    int mt = wave;
    size_t arow = ((size_t)b * NP + mt * 32 + lm) * DQ + lk * 8;
    size_t brow = ((size_t)b * NP + g * 32 + lm) * DQ + lk * 8;
    const u16* L0h = KLThi + arow;
    const u16* L0l = KLTlo + arow;
    const u16* P0h = KP2hi + arow;
    const u16* P0l = KP2lo + arow;
    const u16* X0h = XQhi + brow;
    const u16* X0l = XQlo + brow;
    sh8 xh[2][2], xl[2][2], lh[2][2], llr[2][2], ph[2][2], pl[2][2];
#pragma unroll
    for (int row = 0; row < 2; row++) {
#pragma unroll
      for (int ks = 0; ks < 2; ks++) {
        int o = row * 16 * DQ + ks * 32;
        xh[row][ks] = *(const sh8*)(X0h + o);
        xl[row][ks] = *(const sh8*)(X0l + o);
        lh[row][ks] = *(const sh8*)(L0h + o);
        llr[row][ks] = *(const sh8*)(L0l + o);
        ph[row][ks] = *(const sh8*)(P0h + o);
        pl[row][ks] = *(const sh8*)(P0l + o);
      }
    }
    f32x4 aL[2][2] = {};
    f32x4 aP[2][2] = {};
#pragma unroll
    for (int ks = 0; ks < 2; ks++) {
#pragma unroll
      for (int i = 0; i < 2; i++) {
#pragma unroll
        for (int j = 0; j < 2; j++) {
          aL[i][j] = MFMA(lh[i][ks], xh[j][ks], aL[i][j]);
          aL[i][j] = MFMA(lh[i][ks], xl[j][ks], aL[i][j]);
          aL[i][j] = MFMA(llr[i][ks], xh[j][ks], aL[i][j]);
          aP[i][j] = MFMA(ph[i][ks], xh[j][ks], aP[i][j]);
          aP[i][j] = MFMA(ph[i][ks], xl[j][ks], aP[i][j]);
          aP[i][j] = MFMA(pl[i][ks], xh[j][ks], aP[i][j]);
        }
      }
    }
#pragma unroll
    for (int i = 0; i < 2; i++)
#pragma unroll
      for (int j = 0; j < 2; j++) {
        int nloc = j * 16 + lm;
        int mloc = mt * 32 + i * 16 + lk * 4;
        float4 v;
        v.x = bw * aL[i][j][0] + obw * aP[i][j][0];
        v.y = bw * aL[i][j][1] + obw * aP[i][j][1];
        v.z = bw * aL[i][j][2] + obw * aP[i][j][2];
        v.w = bw * aL[i][j][3] + obw * aP[i][j][3];
        *(float4*)&Esh[nloc * 132 + mloc] = v;
      }
  }
  if (wave < 2) {
    const u16* A0 = XQhi + ((size_t)b * NP + g * 32 + lm) * DQ + lk * 8;
    const u16* A1 = A0 + 16 * DQ;
    const u16* B0 = p1wT + ((size_t)(wave * 32) + lm) * DQ + lk * 8;
    const u16* B1 = B0 + 16 * DQ;
    f32x4 q[2][2] = {};
#pragma unroll
    for (int ks = 0; ks < 2; ks++) {
      int o = ks * 32;
      sh8 a0 = *(const sh8*)(A0 + o), a1 = *(const sh8*)(A1 + o);
      sh8 b0 = *(const sh8*)(B0 + o), b1 = *(const sh8*)(B1 + o);
      q[0][0] = MFMA(a0, b0, q[0][0]);
      q[0][1] = MFMA(a0, b1, q[0][1]);
      q[1][0] = MFMA(a1, b0, q[1][0]);
      q[1][1] = MFMA(a1, b1, q[1][1]);
    }
#pragma unroll
    for (int i = 0; i < 2; i++)
#pragma unroll
      for (int j = 0; j < 2; j++)
#pragma unroll
        for (int r = 0; r < 4; r++)
          q1sh[(i * 16 + lk * 4 + r) * 66 + wave * 32 + j * 16 + lm] = q[i][j][r];
  }
  {
    int n = tid >> 3, o0 = (tid & 7) * 8;
    const u16* xs = XQhi + ((size_t)b * NP + g * 32 + n) * DQ + o0;
    uint2 w0 = *(const uint2*)xs;
    uint2 w1 = *(const uint2*)(xs + 4);
    const u16* hh = (const u16*)&w0;
    const u16* h2 = (const u16*)&w1;
    float s = 0.0f;
#pragma unroll
    for (int k = 0; k < 4; k++) s = fmaf(bf2f(hh[k]), p1b[o0 + k], s);
#pragma unroll
    for (int k = 0; k < 4; k++) s = fmaf(bf2f(h2[k]), p1b[o0 + 4 + k], s);
    s += __shfl_xor(s, 1);
    s += __shfl_xor(s, 2);
    s += __shfl_xor(s, 4);
    if ((tid & 7) == 0) c1sh[n] = s;
  }
  __syncthreads();
  {
    int n = tid >> 3, mc = (tid & 7) * 16;
    size_t asrow = ((size_t)b * NP + g * 32 + n) * NP + mc;
    float idxv[16], bias[16];
    float c1v = c1sh[n];
#pragma unroll
    for (int k4 = 0; k4 < 4; k4++) {
      float4 a4 = *(const float4*)&AS[asrow + k4 * 4];
      idxv[k4 * 4 + 0] = a4.x * ANG_REV;
      idxv[k4 * 4 + 1] = a4.y * ANG_REV;
      idxv[k4 * 4 + 2] = a4.z * ANG_REV;
      idxv[k4 * 4 + 3] = a4.w * ANG_REV;
    }
#pragma unroll
    for (int k = 0; k < 16; k++) bias[k] = c1v;
    for (int j = 0; j < 32; j++) {
      float dv = divs[j];
      float qs = q1sh[n * 66 + 2 * j], qc = q1sh[n * 66 + 2 * j + 1];
#pragma unroll
      for (int k = 0; k < 16; k++) {
        float rev = idxv[k] * dv;   // |rev| <= 0.61 revolutions
        bias[k] = fmaf(qs, hw_sin(rev), bias[k]);
        bias[k] = fmaf(qc, hw_cos(rev), bias[k]);
      }
    }
    float ev[16], mx = -1e30f;
#pragma unroll
    for (int k = 0; k < 16; k++) {
      ev[k] = Esh[n * 132 + mc + k] + bw * bias[k];
      mx = fmaxf(mx, ev[k]);
    }
    mx = fmaxf(mx, __shfl_xor(mx, 1));
    mx = fmaxf(mx, __shfl_xor(mx, 2));
    mx = fmaxf(mx, __shfl_xor(mx, 4));
    float s = 0.0f;
#pragma unroll
    for (int k = 0; k < 16; k++) {
      ev[k] = __expf(ev[k] - mx);
      s += ev[k];
    }
    s += __shfl_xor(s, 1);
    s += __shfl_xor(s, 2);
    s += __shfl_xor(s, 4);
    float inv = 1.0f / s;
#pragma unroll
    for (int k = 0; k < 16; k++) Esh[n * 132 + mc + k] = ev[k] * inv;
  }
  __syncthreads();
  {
    int m = tid >> 1, nc = (tid & 1) * 16;
    float s = 0.0f;
    u16 tmp[16];
#pragma unroll
    for (int k = 0; k < 16; k++) {
      float v = Esh[(nc + k) * 132 + m];
      s += v;
      tmp[k] = f2bf(v);
    }
    u16* dst = PT + ((size_t)b * NP + m) * NP + g * 32 + nc;
    *(uint4*)&dst[0] = *(const uint4*)&tmp[0];
    *(uint4*)&dst[8] = *(const uint4*)&tmp[8];
    s += __shfl_xor(s, 1);
    if ((tid & 1) == 0) SCLp[((size_t)b * 4 + g) * NP + m] = s;
  }
}

// ---------------------------------------------------------------------------
// Merged value epilogue (512 blocks = 8ct x 64b). Per block:
// phase1: wlu = M@x (+WlUP), afp = Wl@x (K=256, x loaded once, afp in VGPRs);
// phase2: acc2 = wlu @ P (K=128, wlu via LDS overlay); epilogue:
// out = x + gelu(BN(afp - acc2*scl + bl)); writes NEXT-layer xT plane (o).
__global__ __launch_bounds__(256) void k_h4(
    const u16* __restrict__ xThi, const u16* __restrict__ Mb,
    const u16* __restrict__ Wlbf, const u16* __restrict__ WlUP,
    const u16* __restrict__ PT, const float* __restrict__ SCLp,
    const float* __restrict__ bl, const float* __restrict__ bng,
    const float* __restrict__ bnb, const float* __restrict__ xsrc, int xbs,
    float* __restrict__ out, int layer,
    u16* __restrict__ xThi_o, u16* __restrict__ xTlo_o)
{
  __shared__ __align__(16) u16 WS[2 * 32 * LROW];
  int ct = blockIdx.x >> 6, b = blockIdx.x & 63;
  int tid = threadIdx.x, lane = tid & 63, wave = tid >> 6;
  int lm = lane & 15, lk = lane >> 4;
  u16* MT = WS;
  u16* WT = WS + 32 * LROW;
  {
    const u16* sM = Mb + (size_t)ct * 32 * CH;
    const u16* sW = Wlbf + (size_t)ct * 32 * CH;
    STAGE_W(MT, sM)
    STAGE_W(WT, sW)
  }
  __syncthreads();
  // phase 1: both K=256 GEMMs share the x operand load
  const u16* X0 = xThi + ((size_t)b * NP + wave * 32 + lm) * CH + lk * 8;
  const u16* X1 = X0 + 16 * CH;
  f32x4 awl[2][2] = {};
  f32x4 afp[2][2] = {};
#pragma unroll
  for (int kb = 0; kb < 2; kb++) {
    sh8 rx0[4], rx1[4];
#pragma unroll
    for (int u = 0; u < 4; u++) {
      int o = (kb * 4 + u) * 32;
      rx0[u] = *(const sh8*)(X0 + o);
      rx1[u] = *(const sh8*)(X1 + o);
    }
#pragma unroll
    for (int u = 0; u < 4; u++) {
      int o2 = (kb * 4 + u) * 32 + lk * 8;
      sh8 m0 = *(const sh8*)&MT[lm * LROW + o2];
      sh8 m1 = *(const sh8*)&MT[(16 + lm) * LROW + o2];
      sh8 w0 = *(const sh8*)&WT[lm * LROW + o2];
      sh8 w1 = *(const sh8*)&WT[(16 + lm) * LROW + o2];
      awl[0][0] = MFMA(m0, rx0[u], awl[0][0]);
      awl[0][1] = MFMA(m0, rx1[u], awl[0][1]);
      awl[1][0] = MFMA(m1, rx0[u], awl[1][0]);
      awl[1][1] = MFMA(m1, rx1[u], awl[1][1]);
      afp[0][0] = MFMA(w0, rx0[u], afp[0][0]);
      afp[0][1] = MFMA(w0, rx1[u], afp[0][1]);
      afp[1][0] = MFMA(w1, rx0[u], afp[1][0]);
      afp[1][1] = MFMA(w1, rx1[u], afp[1][1]);
    }
  }
  __syncthreads();   // MT reads done everywhere
  u16* wluS = WS;    // overlay: [32 c'][136 n]
#pragma unroll
  for (int i = 0; i < 2; i++)
#pragma unroll
    for (int j = 0; j < 2; j++) {
      int cl = i * 16 + lk * 4;
      int n = wave * 32 + j * 16 + lm;
      uint2 up = *(const uint2*)&WlUP[((size_t)b * NP + n) * CH + ct * 32 + cl];
      const u16* uph = (const u16*)&up;
#pragma unroll
      for (int r = 0; r < 4; r++)
        wluS[(cl + r) * 136 + n] = f2bf(awl[i][j][r] + bf2f(uph[r]));
    }
  __syncthreads();
  // phase 2: acc2 = wlu @ P (K=128 over n); B = PT rows m (wave's 32-range)
  const u16* B0 = PT + ((size_t)b * NP + wave * 32 + lm) * NP + lk * 8;
  const u16* B1 = B0 + 16 * NP;
  f32x4 acc2[2][2] = {};
#pragma unroll
  for (int ks = 0; ks < 4; ks++) {
    int o = ks * 32;
    sh8 b0 = *(const sh8*)(B0 + o);
    sh8 b1 = *(const sh8*)(B1 + o);
    int o2 = ks * 32 + lk * 8;
    sh8 a0 = *(const sh8*)&wluS[lm * 136 + o2];
    sh8 a1 = *(const sh8*)&wluS[(16 + lm) * 136 + o2];
    acc2[0][0] = MFMA(a0, b0, acc2[0][0]);
    acc2[0][1] = MFMA(a0, b1, acc2[0][1]);
    acc2[1][0] = MFMA(a1, b0, acc2[1][0]);
    acc2[1][1] = MFMA(a1, b1, acc2[1][1]);
  }
  const float rbn = 0.999995000037499687f;  // 1/sqrt(1+1e-5)
#pragma unroll
  for (int i = 0; i < 2; i++)
#pragma unroll
    for (int j = 0; j < 2; j++) {
      int m = wave * 32 + j * 16 + lm;
      int cq = ct * 32 + i * 16 + lk * 4;
      const float* sp = SCLp + (size_t)b * 4 * NP + m;
      float scl = 1.0f / (1e-12f + sp[0] + sp[NP] + sp[2 * NP] + sp[3 * NP]);
      u16 hh[4], llv[4];
#pragma unroll
      for (int r = 0; r < 4; r++) {
        int c = cq + r;
        float h = afp[i][j][r] - acc2[i][j][r] * scl + bl[c];
        h = h * rbn * bng[c] + bnb[c];
        float gg = 0.5f * h * (1.0f + erff(h * 0.70710678118654752440f));
        float ov = xsrc[(size_t)b * xbs + (size_t)c * NP + m] + gg;
        out[((size_t)b * 4 * CH + (size_t)layer * CH + c) * NP + m] = ov;
        hh[r] = f2bf(ov);
        llv[r] = f2bf(ov - bf2f(hh[r]));
      }
      size_t xoff = ((size_t)b * NP + m) * CH + cq;
      *(uint2*)&xThi_o[xoff] = *(const uint2*)hh;
      *(uint2*)&xTlo_o[xoff] = *(const uint2*)llv;
    }
}

// ---------------------------------------------------------------------------
extern "C" void kernel_launch(void* const* d_in, const int* in_sizes, int n_in,
                              void* d_out, int out_size, void* d_ws, size_t ws_size,
                              hipStream_t stream)
{
  (void)in_sizes; (void)n_in; (void)out_size; (void)ws_size;
  const float* lrf     = (const float*)d_in[0];
  const float* pca     = (const float*)d_in[1];
  const float* a_self  = (const float*)d_in[2];
  const float* a_cross = (const float*)d_in[3];
  const float* Wq  = (const float*)d_in[4];
  const float* Wk  = (const float*)d_in[5];
  const float* Wv  = (const float*)d_in[6];
  const float* Wvp = (const float*)d_in[7];
  const float* Wl  = (const float*)d_in[8];
  const float* bl  = (const float*)d_in[9];
  const float* bng = (const float*)d_in[10];
  const float* bnb = (const float*)d_in[11];
  const float* p1w = (const float*)d_in[12];
  const float* p1b = (const float*)d_in[13];
  const float* p2w = (const float*)d_in[14];
  const float* p2b = (const float*)d_in[15];
  const float* beta_x = (const float*)d_in[16];
  const float* beta_w = (const float*)d_in[17];
  float* out = (float*)d_out;
  float* ws  = (float*)d_ws;

  // ---- workspace carve ----
  const size_t QKN = (size_t)BB * NP * DQ;        // 524288
  const size_t ENN = (size_t)BB * NP * NP;        // 1048576
  const size_t XCN = (size_t)BB * NP * CH;        // 2097152

  float* SCLp = ws;
  u16* up = (u16*)(SCLp + (size_t)BB * 4 * NP);
  u16* xThiA = up;  up += XCN;   // double-buffered x^T planes
  u16* xTloA = up;  up += XCN;
  u16* xThiB = up;  up += XCN;
  u16* xTloB = up;  up += XCN;
  u16* pThi = up;   up += XCN;
  u16* pTlo = up;   up += XCN;
  u16* XQhi = up;   up += QKN;
  u16* XQlo = up;   up += QKN;
  u16* KLThi = up;  up += QKN;
  u16* KLTlo = up;  up += QKN;
  u16* KP2hiA = up; up += (size_t)NLAYERS * QKN;
  u16* KP2loA = up; up += (size_t)NLAYERS * QKN;
  u16* WlUPA = up;  up += (size_t)NLAYERS * XCN;
  u16* PTbf = up;   up += ENN;
  u16* Wlbf = up;   up += (size_t)NLAYERS * CH * CH;
  u16* WvT = up;    up += (size_t)NLAYERS * CH * CH;
  u16* WvpT = up;   up += (size_t)NLAYERS * CH * CH;
  u16* Mb = up;     up += (size_t)NLAYERS * CH * CH;
  u16* M2b = up;    up += (size_t)NLAYERS * CH * CH;
  u16* Wqhi = up;   up += (size_t)NLAYERS * DQ * CH;
  u16* Wqlo = up;   up += (size_t)NLAYERS * DQ * CH;
  u16* Wkhi = up;   up += (size_t)NLAYERS * DQ * CH;
  u16* Wklo = up;   up += (size_t)NLAYERS * DQ * CH;
  u16* p1wT = up;   up += (size_t)NLAYERS * DQ * DQ;
  u16* p2wbf = up;  up += (size_t)NLAYERS * DQ * DQ;
  u16* emb2bf = up; up += QKN;

  // ---- pre-loop (3 launches) ----
  k_init<<<dim3(2568), 256, 0, stream>>>(
      Wv, Wvp, Wl, Wq, Wk, p1w, p2w, pca, lrf, a_cross,
      Wlbf, Wqhi, Wqlo, Wkhi, Wklo, p1wT, p2wbf,
      pThi, pTlo, xThiA, xTloA, WvT, WvpT, emb2bf);
  k_mm<<<dim3(128), 256, 0, stream>>>(WvT, WvpT, Wlbf, beta_x, Mb, M2b);
  k_pre2<<<dim3(2560), 256, 0, stream>>>(
      pThi, pTlo, Wqhi, Wqlo, M2b, p2wbf, emb2bf, p2b,
      KP2hiA, KP2loA, WlUPA);

  // ---- layer loop (3 launches each) ----
  for (int l = 0; l < NLAYERS; l++) {
    const float* xsrc = (l == 0) ? lrf : (out + (size_t)(l - 1) * CH * NP);
    int xbs = (l == 0) ? CH * NP : 4 * CH * NP;
    u16* xhi_in  = (l & 1) ? xThiB : xThiA;
    u16* xlo_in  = (l & 1) ? xTloB : xTloA;
    u16* xhi_out = (l & 1) ? xThiA : xThiB;
    u16* xlo_out = (l & 1) ? xTloA : xTloB;
    k_qk<<<dim3(512), 256, 0, stream>>>(
        xhi_in, xlo_in,
        Wqhi + (size_t)l * DQ * CH, Wqlo + (size_t)l * DQ * CH,
        Wkhi + (size_t)l * DQ * CH, Wklo + (size_t)l * DQ * CH,
        XQhi, XQlo, KLThi, KLTlo);
    k_att<<<dim3(256), 256, 0, stream>>>(
        XQhi, XQlo, KLThi, KLTlo,
        KP2hiA + (size_t)l * QKN, KP2loA + (size_t)l * QKN,
        p1wT + (size_t)l * DQ * DQ, p1b + (size_t)l * DQ,
        a_self, beta_w, l, PTbf, SCLp);
    k_h4<<<dim3(512), 256, 0, stream>>>(
        xhi_in, Mb + (size_t)l * CH * CH, Wlbf + (size_t)l * CH * CH,
        WlUPA + (size_t)l * XCN, PTbf, SCLp,
        bl + (size_t)l * CH, bng + (size_t)l * CH, bnb + (size_t)l * CH,
        xsrc, xbs, out, l, xhi_out, xlo_out);
  }
}